// Round 1
// baseline (8632.709 us; speedup 1.0000x reference)
//
#include <hip/hip_runtime.h>
#include <math.h>

// ---------------- problem constants ----------------
constexpr int Bc = 32, Cch = 3, Hh = 224, Ww = 224, Pp = 16;
constexpr int Dd = 768, NH = 12, DHd = 64, INNERc = 768;
constexpr int DEPTHc = 12, NCLS = 1000;
constexpr int NPc = 196, Nn = 197, PD = 768;   // patches per img, tokens, patch dim
constexpr float EPSf = 1e-5f;

// ---------------- reduction helpers ----------------
__device__ __forceinline__ float wave_red_sum(float v) {
#pragma unroll
    for (int m = 32; m; m >>= 1) v += __shfl_xor(v, m);
    return v;
}

__device__ __forceinline__ void block_red2(float& s, float& s2, float* red) {
    s = wave_red_sum(s);
    s2 = wave_red_sum(s2);
    int wid = threadIdx.x >> 6, lane = threadIdx.x & 63;
    if (lane == 0) { red[wid] = s; red[4 + wid] = s2; }
    __syncthreads();
    s = red[0] + red[1] + red[2] + red[3];
    s2 = red[4] + red[5] + red[6] + red[7];
}

// ---------------- patchify + patch LN ----------------
// out[b*196+n][d], d = p*48 + q*3 + c ; img[b][c][ph*16+p][pw*16+q]
__global__ __launch_bounds__(256) void k_patch_ln(
        const float* __restrict__ img, const float* __restrict__ g,
        const float* __restrict__ bb, float* __restrict__ out) {
    int pid = blockIdx.x;
    int b = pid / NPc, n = pid % NPc;
    int ph = n / 14, pw = n % 14;
    int t = threadIdx.x;
    __shared__ float red[8];
    float v[3];
#pragma unroll
    for (int i = 0; i < 3; i++) {
        int d = t + i * 256;
        int c = d % 3, q = (d / 3) & 15, p = d / 48;
        v[i] = img[((long)(b * Cch + c) * Hh + ph * Pp + p) * Ww + pw * Pp + q];
    }
    float s = v[0] + v[1] + v[2];
    float s2 = v[0] * v[0] + v[1] * v[1] + v[2] * v[2];
    block_red2(s, s2, red);
    float mu = s * (1.f / PD);
    float var = s2 * (1.f / PD) - mu * mu;
    float r = rsqrtf(var + EPSf);
#pragma unroll
    for (int i = 0; i < 3; i++) {
        int d = t + i * 256;
        out[(long)pid * PD + d] = (v[i] - mu) * r * g[d] + bb[d];
    }
}

// ---------------- generic row LayerNorm (768 wide) ----------------
__global__ __launch_bounds__(256) void k_ln(
        const float* __restrict__ in, const float* __restrict__ g,
        const float* __restrict__ bb, float* __restrict__ out,
        long in_stride, long out_stride) {
    long row = blockIdx.x;
    const float* ip = in + row * in_stride;
    float* op = out + row * out_stride;
    int t = threadIdx.x;
    __shared__ float red[8];
    float v[3];
#pragma unroll
    for (int i = 0; i < 3; i++) v[i] = ip[t + i * 256];
    float s = v[0] + v[1] + v[2];
    float s2 = v[0] * v[0] + v[1] * v[1] + v[2] * v[2];
    block_red2(s, s2, red);
    float mu = s * (1.f / Dd);
    float var = s2 * (1.f / Dd) - mu * mu;
    float r = rsqrtf(var + EPSf);
#pragma unroll
    for (int i = 0; i < 3; i++) {
        int d = t + i * 256;
        op[d] = (v[i] - mu) * r * g[d] + bb[d];
    }
}

// ---------------- embed assemble: LN(tmp)+pos, cls+pos ----------------
__global__ __launch_bounds__(256) void k_embed(
        const float* __restrict__ tmp, const float* __restrict__ cls,
        const float* __restrict__ pos, const float* __restrict__ g,
        const float* __restrict__ bb, float* __restrict__ x) {
    int pid = blockIdx.x;  // b*Nn + n
    int b = pid / Nn, n = pid % Nn;
    int t = threadIdx.x;
    float* xp = x + (long)pid * Dd;
    if (n == 0) {
#pragma unroll
        for (int i = 0; i < 3; i++) {
            int d = t + i * 256;
            xp[d] = cls[d] + pos[d];
        }
        return;
    }
    const float* ip = tmp + (long)(b * NPc + n - 1) * Dd;
    __shared__ float red[8];
    float v[3];
#pragma unroll
    for (int i = 0; i < 3; i++) v[i] = ip[t + i * 256];
    float s = v[0] + v[1] + v[2];
    float s2 = v[0] * v[0] + v[1] * v[1] + v[2] * v[2];
    block_red2(s, s2, red);
    float mu = s * (1.f / Dd);
    float var = s2 * (1.f / Dd) - mu * mu;
    float r = rsqrtf(var + EPSf);
#pragma unroll
    for (int i = 0; i < 3; i++) {
        int d = t + i * 256;
        xp[d] = (v[i] - mu) * r * g[d] + bb[d] + pos[(long)n * Dd + d];
    }
}

// ---------------- fp32 tiled GEMM: C = A(MxK) @ W(KxN) [+bias] [+res] ----------------
// BM=BN=64, BK=16, 256 threads, 4x4 micro-tile per thread. K must be mult of 16.
template <int HASB, int HASR>
__global__ __launch_bounds__(256) void k_gemm(
        const float* __restrict__ A, const float* __restrict__ Wt,
        const float* __restrict__ bias, const float* __restrict__ res,
        float* __restrict__ Co, int M, int Nc, int K) {
    __shared__ float As[16][65];
    __shared__ float Bs[16][68];
    int n0 = blockIdx.x * 64, m0 = blockIdx.y * 64;
    int tid = threadIdx.x;
    int tr = tid / 16, tc = tid % 16;
    int am = tid / 4, ak = (tid % 4) * 4;
    int bk = tid / 16, bn = (tid % 16) * 4;
    float acc[4][4] = {};
    bool nfull = (n0 + 64 <= Nc);
    for (int k0 = 0; k0 < K; k0 += 16) {
        float4 av = {0, 0, 0, 0};
        if (m0 + am < M) av = *(const float4*)&A[(long)(m0 + am) * K + k0 + ak];
        As[ak + 0][am] = av.x; As[ak + 1][am] = av.y;
        As[ak + 2][am] = av.z; As[ak + 3][am] = av.w;
        if (nfull) {
            float4 bv = *(const float4*)&Wt[(long)(k0 + bk) * Nc + n0 + bn];
            Bs[bk][bn + 0] = bv.x; Bs[bk][bn + 1] = bv.y;
            Bs[bk][bn + 2] = bv.z; Bs[bk][bn + 3] = bv.w;
        } else {
#pragma unroll
            for (int u = 0; u < 4; u++)
                Bs[bk][bn + u] = (n0 + bn + u < Nc) ? Wt[(long)(k0 + bk) * Nc + n0 + bn + u] : 0.f;
        }
        __syncthreads();
#pragma unroll
        for (int kk = 0; kk < 16; kk++) {
            float a0 = As[kk][tr * 4 + 0], a1 = As[kk][tr * 4 + 1];
            float a2 = As[kk][tr * 4 + 2], a3 = As[kk][tr * 4 + 3];
            float b0 = Bs[kk][tc], b1 = Bs[kk][tc + 16];
            float b2 = Bs[kk][tc + 32], b3 = Bs[kk][tc + 48];
            acc[0][0] += a0 * b0; acc[0][1] += a0 * b1; acc[0][2] += a0 * b2; acc[0][3] += a0 * b3;
            acc[1][0] += a1 * b0; acc[1][1] += a1 * b1; acc[1][2] += a1 * b2; acc[1][3] += a1 * b3;
            acc[2][0] += a2 * b0; acc[2][1] += a2 * b1; acc[2][2] += a2 * b2; acc[2][3] += a2 * b3;
            acc[3][0] += a3 * b0; acc[3][1] += a3 * b1; acc[3][2] += a3 * b2; acc[3][3] += a3 * b3;
        }
        __syncthreads();
    }
#pragma unroll
    for (int i = 0; i < 4; i++) {
        int r = m0 + tr * 4 + i;
        if (r >= M) continue;
#pragma unroll
        for (int j = 0; j < 4; j++) {
            int c0 = n0 + tc + j * 16;
            if (c0 >= Nc) continue;
            float v = acc[i][j];
            if (HASB) v += bias[c0];
            if (HASR) v += res[(long)r * Nc + c0];
            Co[(long)r * Nc + c0] = v;
        }
    }
}

// ---------------- attention scores: dots[bh][i][j] = (q.k)*scale*(1+sph) ----------------
__global__ __launch_bounds__(256) void k_scores(
        const float* __restrict__ qkv, const float* __restrict__ sph,
        float* __restrict__ dots) {
    int bh = blockIdx.z;
    int b = bh / NH, h = bh % NH;
    int i0 = blockIdx.y * 16, j0 = blockIdx.x * 16;
    __shared__ float qs[16][68], ks[16][68];
    int tid = threadIdx.x;
    int r = tid / 16, k4 = (tid % 16) * 4;
    float4 qv = {0, 0, 0, 0}, kv = {0, 0, 0, 0};
    if (i0 + r < Nn) qv = *(const float4*)&qkv[(long)(b * Nn + i0 + r) * 2304 + h * DHd + k4];
    if (j0 + r < Nn) kv = *(const float4*)&qkv[(long)(b * Nn + j0 + r) * 2304 + INNERc + h * DHd + k4];
    qs[r][k4 + 0] = qv.x; qs[r][k4 + 1] = qv.y; qs[r][k4 + 2] = qv.z; qs[r][k4 + 3] = qv.w;
    ks[r][k4 + 0] = kv.x; ks[r][k4 + 1] = kv.y; ks[r][k4 + 2] = kv.z; ks[r][k4 + 3] = kv.w;
    __syncthreads();
    int ti = tid / 16, tj = tid % 16;
    float acc = 0.f;
#pragma unroll
    for (int k = 0; k < DHd; k++) acc += qs[ti][k] * ks[tj][k];
    int i = i0 + ti, j = j0 + tj;
    if (i < Nn && j < Nn)
        dots[((long)bh * Nn + i) * Nn + j] = acc * 0.125f * (1.0f + sph[(long)i * Nn + j]);
}

// ---------------- cross-head normalize: (dw-mu)/sd, ddof=1 over 12 heads ----------------
__global__ __launch_bounds__(256) void k_headnorm(float* __restrict__ dots) {
    int idx = blockIdx.x * 256 + threadIdx.x;
    if (idx >= Nn * Nn) return;
    int b = blockIdx.y;
    long base = (long)b * NH * Nn * Nn + idx;
    float v[NH];
    float s = 0.f;
#pragma unroll
    for (int h = 0; h < NH; h++) { v[h] = dots[base + (long)h * Nn * Nn]; s += v[h]; }
    float mu = s * (1.0f / NH);
    float s2 = 0.f;
#pragma unroll
    for (int h = 0; h < NH; h++) { float d = v[h] - mu; s2 += d * d; }
    float rs = rsqrtf(s2 * (1.0f / (NH - 1)));
#pragma unroll
    for (int h = 0; h < NH; h++) dots[base + (long)h * Nn * Nn] = (v[h] - mu) * rs;
}

// ---------------- row softmax over j (197), one wave per row ----------------
__global__ __launch_bounds__(256) void k_softmax(float* __restrict__ dots) {
    long row = (long)blockIdx.x * 4 + (threadIdx.x >> 6);
    int lane = threadIdx.x & 63;
    if (row >= (long)Bc * NH * Nn) return;
    float* p = dots + row * Nn;
    float v[4];
    float mx = -1e30f;
#pragma unroll
    for (int t = 0; t < 4; t++) {
        int j = lane + t * 64;
        v[t] = (j < Nn) ? p[j] : -1e30f;
        mx = fmaxf(mx, v[t]);
    }
#pragma unroll
    for (int m = 32; m; m >>= 1) mx = fmaxf(mx, __shfl_xor(mx, m));
    float sum = 0.f;
#pragma unroll
    for (int t = 0; t < 4; t++) {
        int j = lane + t * 64;
        v[t] = (j < Nn) ? expf(v[t] - mx) : 0.f;
        sum += v[t];
    }
    sum = wave_red_sum(sum);
    float inv = 1.0f / sum;
#pragma unroll
    for (int t = 0; t < 4; t++) {
        int j = lane + t * 64;
        if (j < Nn) p[j] = v[t] * inv;
    }
}

// ---------------- attn @ v : per (b,h), 16 rows x 64 cols per block ----------------
__global__ __launch_bounds__(256) void k_av(
        const float* __restrict__ dots, const float* __restrict__ qkv,
        float* __restrict__ o) {
    int bh = blockIdx.y;
    int b = bh / NH, h = bh % NH;
    int i0 = blockIdx.x * 16;
    __shared__ float as_[16][17];
    __shared__ float vs[16][68];
    int tid = threadIdx.x;
    int ti = tid / 16, td = tid % 16;
    int lr = tid / 16, ld4 = (tid % 16) * 4;
    float acc[4] = {0, 0, 0, 0};
    for (int j0 = 0; j0 < Nn; j0 += 16) {
        float a = 0.f;
        if (i0 + ti < Nn && j0 + td < Nn)
            a = dots[((long)bh * Nn + i0 + ti) * Nn + j0 + td];
        as_[ti][td] = a;
        float4 vv = {0, 0, 0, 0};
        if (j0 + lr < Nn)
            vv = *(const float4*)&qkv[(long)(b * Nn + j0 + lr) * 2304 + 2 * INNERc + h * DHd + ld4];
        vs[lr][ld4 + 0] = vv.x; vs[lr][ld4 + 1] = vv.y;
        vs[lr][ld4 + 2] = vv.z; vs[lr][ld4 + 3] = vv.w;
        __syncthreads();
#pragma unroll
        for (int jj = 0; jj < 16; jj++) {
            float av = as_[ti][jj];
#pragma unroll
            for (int t = 0; t < 4; t++) acc[t] += av * vs[jj][td + t * 16];
        }
        __syncthreads();
    }
    if (i0 + ti < Nn) {
        float* op = o + ((long)(b * Nn + i0 + ti)) * INNERc + h * DHd;
#pragma unroll
        for (int t = 0; t < 4; t++) op[td + t * 16] = acc[t];
    }
}

// ---------------- host launcher ----------------
extern "C" void kernel_launch(void* const* d_in, const int* in_sizes, int n_in,
                              void* d_out, int out_size, void* d_ws, size_t ws_size,
                              hipStream_t stream) {
    const float* img     = (const float*)d_in[0];
    const float* sph     = (const float*)d_in[1];
    const float* patch_g = (const float*)d_in[2];
    const float* patch_b = (const float*)d_in[3];
    const float* W_patch = (const float*)d_in[4];
    const float* b_patch = (const float*)d_in[5];
    const float* emb_g   = (const float*)d_in[6];
    const float* emb_b   = (const float*)d_in[7];
    const float* pos     = (const float*)d_in[8];
    const float* cls     = (const float*)d_in[9];
    const float* ln_g    = (const float*)d_in[10];
    const float* ln_b    = (const float*)d_in[11];
    const float* W_qkv   = (const float*)d_in[12];
    const float* W_out   = (const float*)d_in[13];
    const float* b_out   = (const float*)d_in[14];
    const float* fin_g   = (const float*)d_in[15];
    const float* fin_b   = (const float*)d_in[16];
    const float* W_head  = (const float*)d_in[17];
    const float* b_head  = (const float*)d_in[18];
    float* out = (float*)d_out;

    float* ws = (float*)d_ws;
    const long SZ_XD = (long)Bc * Nn * Dd;              // 4,841,472 floats
    const long SZ_QKV = (long)Bc * Nn * 3 * INNERc;     // 14,524,416
    const long SZ_DOTS = (long)Bc * NH * Nn * Nn;       // 14,902,656
    float* x    = ws;
    float* xn   = x + SZ_XD;      // doubles as `o` after qkv GEMM
    float* qkv  = xn + SZ_XD;     // doubles as patch-embed tmp
    float* dots = qkv + SZ_QKV;
    float* clsb = dots + SZ_DOTS; // 32x768

    // 1. patchify + patch LN -> xn
    hipLaunchKernelGGL(k_patch_ln, dim3(Bc * NPc), dim3(256), 0, stream,
                       img, patch_g, patch_b, xn);
    // 2. patch GEMM (+b_patch) -> tmp (in qkv buffer)
    hipLaunchKernelGGL((k_gemm<1, 0>), dim3(12, 98), dim3(256), 0, stream,
                       xn, W_patch, b_patch, nullptr, qkv, Bc * NPc, Dd, Dd);
    // 3. emb LN + cls concat + pos add -> x
    hipLaunchKernelGGL(k_embed, dim3(Bc * Nn), dim3(256), 0, stream,
                       qkv, cls, pos, emb_g, emb_b, x);

    for (int l = 0; l < DEPTHc; l++) {
        const float* g  = ln_g + (long)l * Dd;
        const float* bb = ln_b + (long)l * Dd;
        const float* Wq = W_qkv + (long)l * Dd * 3 * INNERc;
        const float* Wo = W_out + (long)l * INNERc * Dd;
        const float* bo = b_out + (long)l * Dd;
        hipLaunchKernelGGL(k_ln, dim3(Bc * Nn), dim3(256), 0, stream,
                           x, g, bb, xn, (long)Dd, (long)Dd);
        hipLaunchKernelGGL((k_gemm<0, 0>), dim3(36, 99), dim3(256), 0, stream,
                           xn, Wq, nullptr, nullptr, qkv, Bc * Nn, 3 * INNERc, Dd);
        hipLaunchKernelGGL(k_scores, dim3(13, 13, Bc * NH), dim3(256), 0, stream,
                           qkv, sph, dots);
        hipLaunchKernelGGL(k_headnorm, dim3((Nn * Nn + 255) / 256, Bc), dim3(256), 0, stream,
                           dots);
        hipLaunchKernelGGL(k_softmax, dim3((Bc * NH * Nn + 3) / 4), dim3(256), 0, stream,
                           dots);
        hipLaunchKernelGGL(k_av, dim3(13, Bc * NH), dim3(256), 0, stream,
                           dots, qkv, xn);
        hipLaunchKernelGGL((k_gemm<1, 1>), dim3(12, 99), dim3(256), 0, stream,
                           xn, Wo, bo, x, x, Bc * Nn, Dd, Dd);
    }
    // final LN on cls rows only
    hipLaunchKernelGGL(k_ln, dim3(Bc), dim3(256), 0, stream,
                       x, fin_g, fin_b, clsb, (long)Nn * Dd, (long)Dd);
    // head GEMM
    hipLaunchKernelGGL((k_gemm<1, 0>), dim3(16, 1), dim3(256), 0, stream,
                       clsb, W_head, b_head, nullptr, out, Bc, NCLS, Dd);
}

// Round 2
// 5273.413 us; speedup vs baseline: 1.6370x; 1.6370x over previous
//
#include <hip/hip_runtime.h>
#include <math.h>

// ---------------- problem constants ----------------
constexpr int Bc = 32, Cch = 3, Hh = 224, Ww = 224, Pp = 16;
constexpr int Dd = 768, NH = 12, DHd = 64, INNERc = 768;
constexpr int DEPTHc = 12, NCLS = 1000;
constexpr int NPc = 196, Nn = 197, PD = 768;
constexpr float EPSf = 1e-5f;

typedef _Float16 half_t;
typedef __attribute__((ext_vector_type(8))) _Float16 half8;
typedef __attribute__((ext_vector_type(4))) float f32x4;

// ---------------- reduction helpers ----------------
__device__ __forceinline__ float wave_red_sum(float v) {
#pragma unroll
    for (int m = 32; m; m >>= 1) v += __shfl_xor(v, m);
    return v;
}

__device__ __forceinline__ void block_red2(float& s, float& s2, float* red) {
    s = wave_red_sum(s);
    s2 = wave_red_sum(s2);
    int wid = threadIdx.x >> 6, lane = threadIdx.x & 63;
    if (lane == 0) { red[wid] = s; red[4 + wid] = s2; }
    __syncthreads();
    s = red[0] + red[1] + red[2] + red[3];
    s2 = red[4] + red[5] + red[6] + red[7];
}

// ---------------- patchify + patch LN -> f16 ----------------
__global__ __launch_bounds__(256) void k_patch_ln(
        const float* __restrict__ img, const float* __restrict__ g,
        const float* __restrict__ bb, half_t* __restrict__ out) {
    int pid = blockIdx.x;
    int b = pid / NPc, n = pid % NPc;
    int ph = n / 14, pw = n % 14;
    int t = threadIdx.x;
    __shared__ float red[8];
    float v[3];
#pragma unroll
    for (int i = 0; i < 3; i++) {
        int d = t + i * 256;
        int c = d % 3, q = (d / 3) & 15, p = d / 48;
        v[i] = img[((long)(b * Cch + c) * Hh + ph * Pp + p) * Ww + pw * Pp + q];
    }
    float s = v[0] + v[1] + v[2];
    float s2 = v[0] * v[0] + v[1] * v[1] + v[2] * v[2];
    block_red2(s, s2, red);
    float mu = s * (1.f / PD);
    float var = s2 * (1.f / PD) - mu * mu;
    float r = rsqrtf(var + EPSf);
#pragma unroll
    for (int i = 0; i < 3; i++) {
        int d = t + i * 256;
        out[(long)pid * PD + d] = (half_t)((v[i] - mu) * r * g[d] + bb[d]);
    }
}

// ---------------- row LayerNorm (768 wide), templated output ----------------
template <typename T>
__global__ __launch_bounds__(256) void k_ln(
        const float* __restrict__ in, const float* __restrict__ g,
        const float* __restrict__ bb, T* __restrict__ out,
        long in_stride, long out_stride) {
    long row = blockIdx.x;
    const float* ip = in + row * in_stride;
    T* op = out + row * out_stride;
    int t = threadIdx.x;
    __shared__ float red[8];
    float v[3];
#pragma unroll
    for (int i = 0; i < 3; i++) v[i] = ip[t + i * 256];
    float s = v[0] + v[1] + v[2];
    float s2 = v[0] * v[0] + v[1] * v[1] + v[2] * v[2];
    block_red2(s, s2, red);
    float mu = s * (1.f / Dd);
    float var = s2 * (1.f / Dd) - mu * mu;
    float r = rsqrtf(var + EPSf);
#pragma unroll
    for (int i = 0; i < 3; i++) {
        int d = t + i * 256;
        op[d] = (T)((v[i] - mu) * r * g[d] + bb[d]);
    }
}

// ---------------- embed assemble: LN(tmp)+pos, cls+pos ----------------
__global__ __launch_bounds__(256) void k_embed(
        const float* __restrict__ tmp, const float* __restrict__ cls,
        const float* __restrict__ pos, const float* __restrict__ g,
        const float* __restrict__ bb, float* __restrict__ x) {
    int pid = blockIdx.x;
    int b = pid / Nn, n = pid % Nn;
    int t = threadIdx.x;
    float* xp = x + (long)pid * Dd;
    if (n == 0) {
#pragma unroll
        for (int i = 0; i < 3; i++) {
            int d = t + i * 256;
            xp[d] = cls[d] + pos[d];
        }
        return;
    }
    const float* ip = tmp + (long)(b * NPc + n - 1) * Dd;
    __shared__ float red[8];
    float v[3];
#pragma unroll
    for (int i = 0; i < 3; i++) v[i] = ip[t + i * 256];
    float s = v[0] + v[1] + v[2];
    float s2 = v[0] * v[0] + v[1] * v[1] + v[2] * v[2];
    block_red2(s, s2, red);
    float mu = s * (1.f / Dd);
    float var = s2 * (1.f / Dd) - mu * mu;
    float r = rsqrtf(var + EPSf);
#pragma unroll
    for (int i = 0; i < 3; i++) {
        int d = t + i * 256;
        xp[d] = (v[i] - mu) * r * g[d] + bb[d] + pos[(long)n * Dd + d];
    }
}

// ---------------- weight prep: fp32 W[K][N] -> f16 Wt[N][K] ----------------
__global__ __launch_bounds__(256) void k_wprep(
        const float* __restrict__ W, half_t* __restrict__ Wt, int K, int N) {
    W += (long)blockIdx.z * K * N;
    Wt += (long)blockIdx.z * K * N;
    __shared__ float tile[32][33];
    int n = blockIdx.x * 32 + threadIdx.x;
    int k0 = blockIdx.y * 32;
#pragma unroll
    for (int i = 0; i < 4; i++)
        tile[threadIdx.y + i * 8][threadIdx.x] = W[(long)(k0 + threadIdx.y + i * 8) * N + n];
    __syncthreads();
    int kk = k0 + threadIdx.x;
#pragma unroll
    for (int i = 0; i < 4; i++)
        Wt[(long)(blockIdx.x * 32 + threadIdx.y + i * 8) * K + kk] =
            (half_t)tile[threadIdx.x][threadIdx.y + i * 8];
}

// ---------------- f16 MFMA GEMM: C(MxN fp32) = A(MxK f16) @ Bt(NxK f16)^T ----------------
// 128x128 tile, BK=64, 256 thr (4 waves, each 64x64). XOR-swizzled LDS (G4).
__device__ __forceinline__ half8 lds_frag(const uint4 (*L)[8], int row, int slot) {
    union { uint4 u; half8 h; } t;
    t.u = L[row][slot];
    return t.h;
}

template <int HASB, int HASR>
__global__ __launch_bounds__(256, 2) void k_hgemm(
        const half_t* __restrict__ A, const half_t* __restrict__ Bt,
        const float* __restrict__ bias, const float* __restrict__ res,
        float* __restrict__ C, int M, int N, int K) {
    __shared__ uint4 As[128][8];
    __shared__ uint4 Bs[128][8];
    const int tid = threadIdx.x;
    const int m0 = blockIdx.y * 128, n0 = blockIdx.x * 128;
    const int lane = tid & 63, w = tid >> 6;
    const int wrr = (w >> 1) * 64, wcc = (w & 1) * 64;
    const int lrow = lane & 15, lgrp = lane >> 4;

    // staging assignment: 4 chunks of A + 4 of B per thread, 16B each
    int lm[4], sw[4];
    long gA[4], gB[4];
    const int cb = (tid & 7) * 8;
#pragma unroll
    for (int c = 0; c < 4; ++c) {
        lm[c] = c * 32 + (tid >> 3);
        sw[c] = (tid & 7) ^ (lm[c] & 7);
        int ma = m0 + lm[c];
        if (ma > M - 1) ma = M - 1;
        gA[c] = (long)ma * K + cb;
        gB[c] = (long)(n0 + lm[c]) * K + cb;  // N is always a multiple of 128
    }

    f32x4 acc[4][4] = {};
    uint4 ra[4], rb[4];

#pragma unroll
    for (int c = 0; c < 4; ++c) { ra[c] = *(const uint4*)(A + gA[c]); rb[c] = *(const uint4*)(Bt + gB[c]); }
#pragma unroll
    for (int c = 0; c < 4; ++c) { As[lm[c]][sw[c]] = ra[c]; Bs[lm[c]][sw[c]] = rb[c]; }
    __syncthreads();

    const int nst = K >> 6;
    for (int t = 0; t < nst; ++t) {
        if (t + 1 < nst) {
            const int k0 = (t + 1) << 6;
#pragma unroll
            for (int c = 0; c < 4; ++c) {
                ra[c] = *(const uint4*)(A + gA[c] + k0);
                rb[c] = *(const uint4*)(Bt + gB[c] + k0);
            }
        }
#pragma unroll
        for (int kh = 0; kh < 2; ++kh) {
            half8 af[4], bf[4];
#pragma unroll
            for (int i = 0; i < 4; ++i) {
                int m = wrr + i * 16 + lrow;
                af[i] = lds_frag(As, m, (kh * 4 + lgrp) ^ (m & 7));
                int n = wcc + i * 16 + lrow;
                bf[i] = lds_frag(Bs, n, (kh * 4 + lgrp) ^ (n & 7));
            }
#pragma unroll
            for (int i = 0; i < 4; ++i)
#pragma unroll
                for (int j = 0; j < 4; ++j)
                    acc[i][j] = __builtin_amdgcn_mfma_f32_16x16x32_f16(af[i], bf[j], acc[i][j], 0, 0, 0);
        }
        if (t + 1 < nst) {
            __syncthreads();
#pragma unroll
            for (int c = 0; c < 4; ++c) { As[lm[c]][sw[c]] = ra[c]; Bs[lm[c]][sw[c]] = rb[c]; }
            __syncthreads();
        }
    }

    // epilogue: C/D layout col=lane&15, row=(lane>>4)*4+q (m89-verified)
#pragma unroll
    for (int i = 0; i < 4; ++i) {
#pragma unroll
        for (int j = 0; j < 4; ++j) {
            int colc = n0 + wcc + j * 16 + lrow;
            float bv = HASB ? bias[colc] : 0.f;
#pragma unroll
            for (int q = 0; q < 4; ++q) {
                int r = m0 + wrr + i * 16 + lgrp * 4 + q;
                if (r < M) {
                    float v = acc[i][j][q] + bv;
                    if (HASR) v += res[(long)r * N + colc];
                    C[(long)r * N + colc] = v;
                }
            }
        }
    }
}

// ---------------- fp32 tiled GEMM (kept for the tiny head GEMM) ----------------
template <int HASB, int HASR>
__global__ __launch_bounds__(256) void k_gemm(
        const float* __restrict__ A, const float* __restrict__ Wt,
        const float* __restrict__ bias, const float* __restrict__ res,
        float* __restrict__ Co, int M, int Nc, int K) {
    __shared__ float As[16][65];
    __shared__ float Bs[16][68];
    int n0 = blockIdx.x * 64, m0 = blockIdx.y * 64;
    int tid = threadIdx.x;
    int tr = tid / 16, tc = tid % 16;
    int am = tid / 4, ak = (tid % 4) * 4;
    int bk = tid / 16, bn = (tid % 16) * 4;
    float acc[4][4] = {};
    bool nfull = (n0 + 64 <= Nc);
    for (int k0 = 0; k0 < K; k0 += 16) {
        float4 av = {0, 0, 0, 0};
        if (m0 + am < M) av = *(const float4*)&A[(long)(m0 + am) * K + k0 + ak];
        As[ak + 0][am] = av.x; As[ak + 1][am] = av.y;
        As[ak + 2][am] = av.z; As[ak + 3][am] = av.w;
        if (nfull) {
            float4 bv = *(const float4*)&Wt[(long)(k0 + bk) * Nc + n0 + bn];
            Bs[bk][bn + 0] = bv.x; Bs[bk][bn + 1] = bv.y;
            Bs[bk][bn + 2] = bv.z; Bs[bk][bn + 3] = bv.w;
        } else {
#pragma unroll
            for (int u = 0; u < 4; u++)
                Bs[bk][bn + u] = (n0 + bn + u < Nc) ? Wt[(long)(k0 + bk) * Nc + n0 + bn + u] : 0.f;
        }
        __syncthreads();
#pragma unroll
        for (int kk = 0; kk < 16; kk++) {
            float a0 = As[kk][tr * 4 + 0], a1 = As[kk][tr * 4 + 1];
            float a2 = As[kk][tr * 4 + 2], a3 = As[kk][tr * 4 + 3];
            float b0 = Bs[kk][tc], b1 = Bs[kk][tc + 16];
            float b2 = Bs[kk][tc + 32], b3 = Bs[kk][tc + 48];
            acc[0][0] += a0 * b0; acc[0][1] += a0 * b1; acc[0][2] += a0 * b2; acc[0][3] += a0 * b3;
            acc[1][0] += a1 * b0; acc[1][1] += a1 * b1; acc[1][2] += a1 * b2; acc[1][3] += a1 * b3;
            acc[2][0] += a2 * b0; acc[2][1] += a2 * b1; acc[2][2] += a2 * b2; acc[2][3] += a2 * b3;
            acc[3][0] += a3 * b0; acc[3][1] += a3 * b1; acc[3][2] += a3 * b2; acc[3][3] += a3 * b3;
        }
        __syncthreads();
    }
#pragma unroll
    for (int i = 0; i < 4; i++) {
        int r = m0 + tr * 4 + i;
        if (r >= M) continue;
#pragma unroll
        for (int j = 0; j < 4; j++) {
            int c0 = n0 + tc + j * 16;
            if (c0 >= Nc) continue;
            float v = acc[i][j];
            if (HASB) v += bias[c0];
            if (HASR) v += res[(long)r * Nc + c0];
            Co[(long)r * Nc + c0] = v;
        }
    }
}

// ---------------- attention scores ----------------
__global__ __launch_bounds__(256) void k_scores(
        const float* __restrict__ qkv, const float* __restrict__ sph,
        float* __restrict__ dots) {
    int bh = blockIdx.z;
    int b = bh / NH, h = bh % NH;
    int i0 = blockIdx.y * 16, j0 = blockIdx.x * 16;
    __shared__ float qs[16][68], ks[16][68];
    int tid = threadIdx.x;
    int r = tid / 16, k4 = (tid % 16) * 4;
    float4 qv = {0, 0, 0, 0}, kv = {0, 0, 0, 0};
    if (i0 + r < Nn) qv = *(const float4*)&qkv[(long)(b * Nn + i0 + r) * 2304 + h * DHd + k4];
    if (j0 + r < Nn) kv = *(const float4*)&qkv[(long)(b * Nn + j0 + r) * 2304 + INNERc + h * DHd + k4];
    qs[r][k4 + 0] = qv.x; qs[r][k4 + 1] = qv.y; qs[r][k4 + 2] = qv.z; qs[r][k4 + 3] = qv.w;
    ks[r][k4 + 0] = kv.x; ks[r][k4 + 1] = kv.y; ks[r][k4 + 2] = kv.z; ks[r][k4 + 3] = kv.w;
    __syncthreads();
    int ti = tid / 16, tj = tid % 16;
    float acc = 0.f;
#pragma unroll
    for (int k = 0; k < DHd; k++) acc += qs[ti][k] * ks[tj][k];
    int i = i0 + ti, j = j0 + tj;
    if (i < Nn && j < Nn)
        dots[((long)bh * Nn + i) * Nn + j] = acc * 0.125f * (1.0f + sph[(long)i * Nn + j]);
}

// ---------------- cross-head normalize ----------------
__global__ __launch_bounds__(256) void k_headnorm(float* __restrict__ dots) {
    int idx = blockIdx.x * 256 + threadIdx.x;
    if (idx >= Nn * Nn) return;
    int b = blockIdx.y;
    long base = (long)b * NH * Nn * Nn + idx;
    float v[NH];
    float s = 0.f;
#pragma unroll
    for (int h = 0; h < NH; h++) { v[h] = dots[base + (long)h * Nn * Nn]; s += v[h]; }
    float mu = s * (1.0f / NH);
    float s2 = 0.f;
#pragma unroll
    for (int h = 0; h < NH; h++) { float d = v[h] - mu; s2 += d * d; }
    float rs = rsqrtf(s2 * (1.0f / (NH - 1)));
#pragma unroll
    for (int h = 0; h < NH; h++) dots[base + (long)h * Nn * Nn] = (v[h] - mu) * rs;
}

// ---------------- row softmax ----------------
__global__ __launch_bounds__(256) void k_softmax(float* __restrict__ dots) {
    long row = (long)blockIdx.x * 4 + (threadIdx.x >> 6);
    int lane = threadIdx.x & 63;
    if (row >= (long)Bc * NH * Nn) return;
    float* p = dots + row * Nn;
    float v[4];
    float mx = -1e30f;
#pragma unroll
    for (int t = 0; t < 4; t++) {
        int j = lane + t * 64;
        v[t] = (j < Nn) ? p[j] : -1e30f;
        mx = fmaxf(mx, v[t]);
    }
#pragma unroll
    for (int m = 32; m; m >>= 1) mx = fmaxf(mx, __shfl_xor(mx, m));
    float sum = 0.f;
#pragma unroll
    for (int t = 0; t < 4; t++) {
        int j = lane + t * 64;
        v[t] = (j < Nn) ? expf(v[t] - mx) : 0.f;
        sum += v[t];
    }
    sum = wave_red_sum(sum);
    float inv = 1.0f / sum;
#pragma unroll
    for (int t = 0; t < 4; t++) {
        int j = lane + t * 64;
        if (j < Nn) p[j] = v[t] * inv;
    }
}

// ---------------- attn @ v -> f16 output ----------------
__global__ __launch_bounds__(256) void k_av(
        const float* __restrict__ dots, const float* __restrict__ qkv,
        half_t* __restrict__ o) {
    int bh = blockIdx.y;
    int b = bh / NH, h = bh % NH;
    int i0 = blockIdx.x * 16;
    __shared__ float as_[16][17];
    __shared__ float vs[16][68];
    int tid = threadIdx.x;
    int ti = tid / 16, td = tid % 16;
    int lr = tid / 16, ld4 = (tid % 16) * 4;
    float acc[4] = {0, 0, 0, 0};
    for (int j0 = 0; j0 < Nn; j0 += 16) {
        float a = 0.f;
        if (i0 + ti < Nn && j0 + td < Nn)
            a = dots[((long)bh * Nn + i0 + ti) * Nn + j0 + td];
        as_[ti][td] = a;
        float4 vv = {0, 0, 0, 0};
        if (j0 + lr < Nn)
            vv = *(const float4*)&qkv[(long)(b * Nn + j0 + lr) * 2304 + 2 * INNERc + h * DHd + ld4];
        vs[lr][ld4 + 0] = vv.x; vs[lr][ld4 + 1] = vv.y;
        vs[lr][ld4 + 2] = vv.z; vs[lr][ld4 + 3] = vv.w;
        __syncthreads();
#pragma unroll
        for (int jj = 0; jj < 16; jj++) {
            float av = as_[ti][jj];
#pragma unroll
            for (int t = 0; t < 4; t++) acc[t] += av * vs[jj][td + t * 16];
        }
        __syncthreads();
    }
    if (i0 + ti < Nn) {
        half_t* op = o + ((long)(b * Nn + i0 + ti)) * INNERc + h * DHd;
#pragma unroll
        for (int t = 0; t < 4; t++) op[td + t * 16] = (half_t)acc[t];
    }
}

// ---------------- host launcher ----------------
extern "C" void kernel_launch(void* const* d_in, const int* in_sizes, int n_in,
                              void* d_out, int out_size, void* d_ws, size_t ws_size,
                              hipStream_t stream) {
    const float* img     = (const float*)d_in[0];
    const float* sph     = (const float*)d_in[1];
    const float* patch_g = (const float*)d_in[2];
    const float* patch_b = (const float*)d_in[3];
    const float* W_patch = (const float*)d_in[4];
    const float* b_patch = (const float*)d_in[5];
    const float* emb_g   = (const float*)d_in[6];
    const float* emb_b   = (const float*)d_in[7];
    const float* pos     = (const float*)d_in[8];
    const float* cls     = (const float*)d_in[9];
    const float* ln_g    = (const float*)d_in[10];
    const float* ln_b    = (const float*)d_in[11];
    const float* W_qkv   = (const float*)d_in[12];
    const float* W_out   = (const float*)d_in[13];
    const float* b_out   = (const float*)d_in[14];
    const float* fin_g   = (const float*)d_in[15];
    const float* fin_b   = (const float*)d_in[16];
    const float* W_head  = (const float*)d_in[17];
    const float* b_head  = (const float*)d_in[18];
    float* out = (float*)d_out;

    const long SZ_XD   = (long)Bc * Nn * Dd;          // 4,841,472
    const long SZ_QKV  = (long)Bc * Nn * 3 * INNERc;  // 14,524,416
    const long SZ_DOTS = (long)Bc * NH * Nn * Nn;     // 14,902,656

    float* ws   = (float*)d_ws;
    float* x    = ws;
    float* qkv  = x + SZ_XD;       // also patch-embed tmp (fp32)
    float* dots = qkv + SZ_QKV;
    float* clsb = dots + SZ_DOTS;  // 32x768
    half_t* xh       = (half_t*)(clsb + 32 * 768);     // f16 activations (LN out / AV out)
    half_t* wt_patch = xh + SZ_XD;                     // 768x768
    half_t* wt_qkv   = wt_patch + (long)Dd * Dd;       // 12 x 2304x768
    half_t* wt_out   = wt_qkv + (long)DEPTHc * 3 * INNERc * Dd;  // 12 x 768x768

    // ---- weight prep: fp32 [K][N] -> f16 [N][K] ----
    hipLaunchKernelGGL(k_wprep, dim3(Dd / 32, Dd / 32, 1), dim3(32, 8), 0, stream,
                       W_patch, wt_patch, Dd, Dd);
    hipLaunchKernelGGL(k_wprep, dim3(3 * INNERc / 32, Dd / 32, DEPTHc), dim3(32, 8), 0, stream,
                       W_qkv, wt_qkv, Dd, 3 * INNERc);
    hipLaunchKernelGGL(k_wprep, dim3(Dd / 32, Dd / 32, DEPTHc), dim3(32, 8), 0, stream,
                       W_out, wt_out, Dd, Dd);

    // 1. patchify + patch LN -> xh (f16)
    hipLaunchKernelGGL(k_patch_ln, dim3(Bc * NPc), dim3(256), 0, stream,
                       img, patch_g, patch_b, xh);
    // 2. patch GEMM (+b_patch) -> tmp fp32 (in qkv buffer)
    hipLaunchKernelGGL((k_hgemm<1, 0>), dim3(6, 49), dim3(256), 0, stream,
                       xh, wt_patch, b_patch, nullptr, qkv, Bc * NPc, Dd, Dd);
    // 3. emb LN + cls concat + pos add -> x
    hipLaunchKernelGGL(k_embed, dim3(Bc * Nn), dim3(256), 0, stream,
                       qkv, cls, pos, emb_g, emb_b, x);

    const int Mrows = Bc * Nn;  // 6304
    for (int l = 0; l < DEPTHc; l++) {
        const float* g  = ln_g + (long)l * Dd;
        const float* bb = ln_b + (long)l * Dd;
        const half_t* Wq = wt_qkv + (long)l * 3 * INNERc * Dd;
        const half_t* Wo = wt_out + (long)l * Dd * Dd;
        const float* bo = b_out + (long)l * Dd;
        hipLaunchKernelGGL((k_ln<half_t>), dim3(Mrows), dim3(256), 0, stream,
                           x, g, bb, xh, (long)Dd, (long)Dd);
        hipLaunchKernelGGL((k_hgemm<0, 0>), dim3(18, 50), dim3(256), 0, stream,
                           xh, Wq, nullptr, nullptr, qkv, Mrows, 3 * INNERc, Dd);
        hipLaunchKernelGGL(k_scores, dim3(13, 13, Bc * NH), dim3(256), 0, stream,
                           qkv, sph, dots);
        hipLaunchKernelGGL(k_headnorm, dim3((Nn * Nn + 255) / 256, Bc), dim3(256), 0, stream,
                           dots);
        hipLaunchKernelGGL(k_softmax, dim3((Bc * NH * Nn + 3) / 4), dim3(256), 0, stream,
                           dots);
        hipLaunchKernelGGL(k_av, dim3(13, Bc * NH), dim3(256), 0, stream,
                           dots, qkv, xh);
        hipLaunchKernelGGL((k_hgemm<1, 1>), dim3(6, 50), dim3(256), 0, stream,
                           xh, Wo, bo, x, x, Mrows, Dd, Dd);
    }
    // final LN (cls rows only) -> clsb fp32
    hipLaunchKernelGGL((k_ln<float>), dim3(Bc), dim3(256), 0, stream,
                       x, fin_g, fin_b, clsb, (long)Nn * Dd, (long)Dd);
    // head GEMM (fp32, tiny)
    hipLaunchKernelGGL((k_gemm<1, 0>), dim3(16, 1), dim3(256), 0, stream,
                       clsb, W_head, b_head, nullptr, out, Bc, NCLS, Dd);
}